// Round 16
// baseline (63.539 us; speedup 1.0000x reference)
//
#include <hip/hip_runtime.h>

#define NT 256
#define NBLK 2048            // 8 blocks/CU * 256 CU; 2048 threads/CU, 4-wave blocks
#define NBUCK 1024
#define CNT_SHIFT 40
#define EXP_SCALE 2048.0f
#define EXP_MASK ((1ull << CNT_SHIFT) - 1)

static __device__ __forceinline__ float clip10(float x) {
    return fminf(10.0f, fmaxf(-10.0f, x));
}

// Process one sample: pack (censor << 40) | round(exp(clip(lr)) * 2^11) and
// ds_add_u64 it into the LDS histogram. Bounds: cnt <= 8.4M < 2^24;
// exp-sum ~1.4e7*2048 ~= 2.9e10 << 2^40. e*2048+0.5 < 2^26 -> u32 cvt exact.
#define PROC1(LV, TV, CV) do {                                              \
    float lv_ = clip10(LV);                                                 \
    float e_ = __expf(lv_);                                                 \
    unsigned b_ = (unsigned)((TV) * fB);                                    \
    if (b_ >= NBUCK) b_ = NBUCK - 1;                                        \
    unsigned long long pk_ = ((unsigned long long)((CV) & 1) << CNT_SHIFT)  \
                           | (unsigned long long)(unsigned)(e_ * EXP_SCALE + 0.5f); \
    if ((CV) == 1) lsum += lv_;                                             \
    atomicAdd(&h[b_], pk_);                                                 \
} while (0)

#define PROC4(L, T, C) do {                                                 \
    PROC1((L).x, (T).x, (C).x); PROC1((L).y, (T).y, (C).y);                 \
    PROC1((L).z, (T).z, (C).z); PROC1((L).w, (T).w, (C).w);                 \
} while (0)

// Pass 1: streaming LDS histogram. Flat specialized path for the exact shape
// (4 float4-groups per thread, stride NBLK*NT unchanged); 256-thread blocks
// give 8 blocks/CU -> finer residency granularity, shorter barriers, smaller
// flush tails than the 1024-thread variant (whose measured occupancy was 28%).
__global__ __launch_bounds__(NT, 8)
void cox_pass1(const float* __restrict__ lr, const float* __restrict__ tm,
               const int* __restrict__ cen, unsigned long long* __restrict__ bucket,
               double* __restrict__ bsum, int n) {
    __shared__ unsigned long long h[NBUCK];
    __shared__ double swave[NT / 64];
    for (int idx = threadIdx.x; idx < NBUCK; idx += NT) h[idx] = 0ull;
    __syncthreads();

    const int n4 = n >> 2;
    const int stride = gridDim.x * NT;
    const float fB = (float)NBUCK;
    float lsum = 0.0f;

    const float4* LR4 = (const float4*)lr;
    const float4* TM4 = (const float4*)tm;
    const int4*   CE4 = (const int4*)cen;

    int i = blockIdx.x * NT + threadIdx.x;
    if ((n & 3) == 0 && n4 == 4 * stride) {
        // Exact harness shape: every thread owns groups i, i+s, i+2s, i+3s.
        float4 l0 = LR4[i];
        float4 l1 = LR4[i + stride];
        float4 l2 = LR4[i + 2 * stride];
        float4 l3 = LR4[i + 3 * stride];
        float4 t0 = TM4[i];
        float4 t1 = TM4[i + stride];
        float4 t2 = TM4[i + 2 * stride];
        float4 t3 = TM4[i + 3 * stride];
        int4   c0 = CE4[i];
        int4   c1 = CE4[i + stride];
        int4   c2 = CE4[i + 2 * stride];
        int4   c3 = CE4[i + 3 * stride];
        PROC4(l0, t0, c0);
        PROC4(l1, t1, c1);
        PROC4(l2, t2, c2);
        PROC4(l3, t3, c3);
    } else {
        // Generic fallback: grid-stride over float4 groups.
        for (; i < n4; i += stride) {
            float4 l = LR4[i];
            float4 t = TM4[i];
            int4  cz = CE4[i];
            PROC4(l, t, cz);
        }
        if (blockIdx.x == 0 && threadIdx.x == 0) {   // tail (n % 4 != 0)
            for (int k = n4 << 2; k < n; ++k) {
                float tvk = tm[k];
                float lvk = lr[k];
                int   cvk = cen[k];
                PROC1(lvk, tvk, cvk);
            }
        }
    }
    __syncthreads();

    // Flush: one packed u64 atomic per bucket, 4 per thread (fire-and-forget).
    for (int idx = threadIdx.x; idx < NBUCK; idx += NT)
        atomicAdd(&bucket[idx], h[idx]);

    // lr-sum: wave shuffle, fold wave partials -> one double per block.
    double d = (double)lsum;
    #pragma unroll
    for (int off = 32; off > 0; off >>= 1)
        d += __shfl_down(d, off, 64);
    if ((threadIdx.x & 63) == 0) swave[threadIdx.x >> 6] = d;
    __syncthreads();
    if (threadIdx.x == 0) {
        double acc = 0.0;
        #pragma unroll
        for (int w = 0; w < NT / 64; ++w) acc += swave[w];
        bsum[blockIdx.x] = acc;
    }
}

// Pass 2: single block (256 threads). Unpack the 1024 packed buckets,
// suffix-inclusive scan of exp sums, dot = sum_b cnt_b*log(cum_b + 1e-15),
// fold per-block lr sums, then loss = -(sum_lr - dot)/n_events.
__global__ void cox_scanfinal(const unsigned long long* __restrict__ bucket,
                              const double* __restrict__ bsum, int nblk,
                              float* __restrict__ out) {
    int t = threadIdx.x;
    float v[4], c[4];
    float s = 0.0f;
    #pragma unroll
    for (int j = 0; j < 4; ++j) {
        unsigned long long pk = bucket[t * 4 + j];
        v[j] = (float)((double)(pk & EXP_MASK) * (1.0 / (double)EXP_SCALE));
        c[j] = (float)(unsigned)(pk >> CNT_SHIFT);
        s += v[j];
    }
    double wacc = 0.0;
    for (int k = t; k < nblk; k += 256) wacc += bsum[k];

    __shared__ float sh[256];
    sh[t] = s;
    __syncthreads();
    for (int d = 1; d < 256; d <<= 1) {
        float add = (t >= d) ? sh[t - d] : 0.0f;
        __syncthreads();
        sh[t] += add;
        __syncthreads();
    }
    float total = sh[255];
    float run = total - sh[t];          // sum over threads strictly after t
    double dot = 0.0;
    float cs = 0.0f;
    #pragma unroll
    for (int j = 3; j >= 0; --j) {
        run += v[j];                    // suffix-inclusive cum at bucket t*4+j
        dot += (double)(c[j] * logf(run + 1e-15f));
        cs  += c[j];
    }
    __shared__ double sdd[256];
    __shared__ double swl[256];
    __shared__ float scc[256];
    sdd[t] = dot; swl[t] = wacc; scc[t] = cs;
    __syncthreads();
    for (int d = 128; d > 0; d >>= 1) {
        if (t < d) { sdd[t] += sdd[t + d]; swl[t] += swl[t + d]; scc[t] += scc[t + d]; }
        __syncthreads();
    }
    if (t == 0) {
        double tot = swl[0] - sdd[0];
        double denom = (scc[0] < 1.0f) ? 1.0 : (double)scc[0];
        out[0] = (float)(-tot / denom);
    }
}

extern "C" void kernel_launch(void* const* d_in, const int* in_sizes, int n_in,
                              void* d_out, int out_size, void* d_ws, size_t ws_size,
                              hipStream_t stream) {
    const float* lr  = (const float*)d_in[0];
    const float* tm  = (const float*)d_in[1];
    const int*   cen = (const int*)d_in[2];
    float* out = (float*)d_out;
    int n = in_sizes[0];

    unsigned long long* bucket = (unsigned long long*)d_ws;
    double* bsum = (double*)(bucket + NBUCK);   // 8 KB offset, 8-aligned

    hipMemsetAsync(bucket, 0, (size_t)NBUCK * 8, stream);
    cox_pass1<<<NBLK, NT, 0, stream>>>(lr, tm, cen, bucket, bsum, n);
    cox_scanfinal<<<1, 256, 0, stream>>>(bucket, bsum, NBLK, out);
}

// Round 17
// 33.877 us; speedup vs baseline: 1.8756x; 1.8756x over previous
//
#include <hip/hip_runtime.h>

#define NT 1024
#define NBLK 512             // 2 blocks/CU * 256 CU; 2048 threads/CU
#define NBUCK 1024
#define CNT_SHIFT 40
#define EXP_SCALE 2048.0f
#define EXP_MASK ((1ull << CNT_SHIFT) - 1)

static __device__ __forceinline__ float clip10(float x) {
    return fminf(10.0f, fmaxf(-10.0f, x));
}

// Process one sample: pack (censor << 40) | round(exp(clip(lr)) * 2^11) and
// ds_add_u64 it into the LDS histogram. Bounds: cnt <= 8.4M < 2^24;
// exp-sum ~1.4e7*2048 ~= 2.9e10 << 2^40.
#define PROC1(LV, TV, CV) do {                                              \
    float lv_ = clip10(LV);                                                 \
    float e_ = __expf(lv_);                                                 \
    unsigned b_ = (unsigned)((TV) * fB);                                    \
    if (b_ >= NBUCK) b_ = NBUCK - 1;                                        \
    unsigned long long pk_ = ((unsigned long long)((CV) & 1) << CNT_SHIFT)  \
                           | (unsigned long long)(e_ * EXP_SCALE + 0.5f);   \
    if ((CV) == 1) lsum += lv_;                                             \
    atomicAdd(&h[b_], pk_);                                                 \
} while (0)

#define PROC4(L, T, C) do {                                                 \
    PROC1((L).x, (T).x, (C).x); PROC1((L).y, (T).y, (C).y);                 \
    PROC1((L).z, (T).z, (C).z); PROC1((L).w, (T).w, (C).w);                 \
} while (0)

// Pass 1: streaming LDS histogram. Specialized flat path for the exact shape
// (4 float4-groups per thread): all 12 loads issued as named registers before
// any use. Measured optimum geometry: 512 blocks x 1024 threads (round 14,
// 33.4us); finer blocks quadruple flush atomics and regress 2x (round 16).
__global__ __launch_bounds__(NT, 4)
void cox_pass1(const float* __restrict__ lr, const float* __restrict__ tm,
               const int* __restrict__ cen, unsigned long long* __restrict__ bucket,
               double* __restrict__ bsum, int n) {
    __shared__ unsigned long long h[NBUCK];
    __shared__ double swave[NT / 64];
    for (int idx = threadIdx.x; idx < NBUCK; idx += NT) h[idx] = 0ull;
    __syncthreads();

    const int n4 = n >> 2;
    const int stride = gridDim.x * NT;
    const float fB = (float)NBUCK;
    float lsum = 0.0f;

    const float4* LR4 = (const float4*)lr;
    const float4* TM4 = (const float4*)tm;
    const int4*   CE4 = (const int4*)cen;

    int i = blockIdx.x * NT + threadIdx.x;
    if ((n & 3) == 0 && n4 == 4 * stride) {
        // Exact harness shape: every thread owns groups i, i+s, i+2s, i+3s.
        float4 l0 = LR4[i];
        float4 l1 = LR4[i + stride];
        float4 l2 = LR4[i + 2 * stride];
        float4 l3 = LR4[i + 3 * stride];
        float4 t0 = TM4[i];
        float4 t1 = TM4[i + stride];
        float4 t2 = TM4[i + 2 * stride];
        float4 t3 = TM4[i + 3 * stride];
        int4   c0 = CE4[i];
        int4   c1 = CE4[i + stride];
        int4   c2 = CE4[i + 2 * stride];
        int4   c3 = CE4[i + 3 * stride];
        PROC4(l0, t0, c0);
        PROC4(l1, t1, c1);
        PROC4(l2, t2, c2);
        PROC4(l3, t3, c3);
    } else {
        // Generic fallback: grid-stride over float4 groups.
        for (; i < n4; i += stride) {
            float4 l = LR4[i];
            float4 t = TM4[i];
            int4  cz = CE4[i];
            PROC4(l, t, cz);
        }
        if (blockIdx.x == 0 && threadIdx.x == 0) {   // tail (n % 4 != 0)
            for (int k = n4 << 2; k < n; ++k) {
                float tvk = tm[k];
                float lvk = lr[k];
                int   cvk = cen[k];
                PROC1(lvk, tvk, cvk);
            }
        }
    }
    __syncthreads();

    // Flush: one packed u64 atomic per bucket (NT >= NBUCK: one op/thread).
    if (threadIdx.x < NBUCK)
        atomicAdd(&bucket[threadIdx.x], h[threadIdx.x]);

    // lr-sum: wave shuffle, fold wave partials -> one double per block.
    double d = (double)lsum;
    #pragma unroll
    for (int off = 32; off > 0; off >>= 1)
        d += __shfl_down(d, off, 64);
    if ((threadIdx.x & 63) == 0) swave[threadIdx.x >> 6] = d;
    __syncthreads();
    if (threadIdx.x == 0) {
        double acc = 0.0;
        #pragma unroll
        for (int w = 0; w < NT / 64; ++w) acc += swave[w];
        bsum[blockIdx.x] = acc;
    }
}

// Pass 2: single block (256 threads). Unpack the 1024 packed buckets,
// suffix-inclusive scan of exp sums, dot = sum_b cnt_b*log(cum_b + 1e-15),
// fold per-block lr sums, then loss = -(sum_lr - dot)/n_events.
__global__ void cox_scanfinal(const unsigned long long* __restrict__ bucket,
                              const double* __restrict__ bsum, int nblk,
                              float* __restrict__ out) {
    int t = threadIdx.x;
    float v[4], c[4];
    float s = 0.0f;
    #pragma unroll
    for (int j = 0; j < 4; ++j) {
        unsigned long long pk = bucket[t * 4 + j];
        v[j] = (float)((double)(pk & EXP_MASK) * (1.0 / (double)EXP_SCALE));
        c[j] = (float)(unsigned)(pk >> CNT_SHIFT);
        s += v[j];
    }
    double wacc = 0.0;
    for (int k = t; k < nblk; k += 256) wacc += bsum[k];

    __shared__ float sh[256];
    sh[t] = s;
    __syncthreads();
    for (int d = 1; d < 256; d <<= 1) {
        float add = (t >= d) ? sh[t - d] : 0.0f;
        __syncthreads();
        sh[t] += add;
        __syncthreads();
    }
    float total = sh[255];
    float run = total - sh[t];          // sum over threads strictly after t
    double dot = 0.0;
    float cs = 0.0f;
    #pragma unroll
    for (int j = 3; j >= 0; --j) {
        run += v[j];                    // suffix-inclusive cum at bucket t*4+j
        dot += (double)(c[j] * logf(run + 1e-15f));
        cs  += c[j];
    }
    __shared__ double sdd[256];
    __shared__ double swl[256];
    __shared__ float scc[256];
    sdd[t] = dot; swl[t] = wacc; scc[t] = cs;
    __syncthreads();
    for (int d = 128; d > 0; d >>= 1) {
        if (t < d) { sdd[t] += sdd[t + d]; swl[t] += swl[t + d]; scc[t] += scc[t + d]; }
        __syncthreads();
    }
    if (t == 0) {
        double tot = swl[0] - sdd[0];
        double denom = (scc[0] < 1.0f) ? 1.0 : (double)scc[0];
        out[0] = (float)(-tot / denom);
    }
}

extern "C" void kernel_launch(void* const* d_in, const int* in_sizes, int n_in,
                              void* d_out, int out_size, void* d_ws, size_t ws_size,
                              hipStream_t stream) {
    const float* lr  = (const float*)d_in[0];
    const float* tm  = (const float*)d_in[1];
    const int*   cen = (const int*)d_in[2];
    float* out = (float*)d_out;
    int n = in_sizes[0];

    unsigned long long* bucket = (unsigned long long*)d_ws;
    double* bsum = (double*)(bucket + NBUCK);   // 8 KB offset, 8-aligned

    hipMemsetAsync(bucket, 0, (size_t)NBUCK * 8, stream);
    cox_pass1<<<NBLK, NT, 0, stream>>>(lr, tm, cen, bucket, bsum, n);
    cox_scanfinal<<<1, 256, 0, stream>>>(bucket, bsum, NBLK, out);
}